// Round 4
// baseline (263.991 us; speedup 1.0000x reference)
//
#include <hip/hip_runtime.h>
#include <cstdint>
#include <cstddef>

typedef __bf16 bf16x8 __attribute__((ext_vector_type(8)));
typedef float f32x4 __attribute__((ext_vector_type(4)));
typedef float f32x16 __attribute__((ext_vector_type(16)));
typedef unsigned short u16;
typedef unsigned int u32;

static constexpr int Bn = 2;       // batch
static constexpr int L  = 2048;    // sequence
static constexpr int Dm = 1024;    // model dim
static constexpr int H  = 16;      // heads
static constexpr int DH = 64;      // head dim
static constexpr int M  = Bn * L;  // 4096 rows

#define SC 0.18033688f   /* 0.125 * log2(e): folded into Q so QK^T is in exp2 domain */

__device__ __forceinline__ u16 f2bf(float f) {
    union { float f; u32 u; } v; v.f = f;
    u32 u = v.u + 0x7FFFu + ((v.u >> 16) & 1u);   // RNE
    return (u16)(u >> 16);
}

// packed f32x2 -> bf16x2 (low = a). HW v_cvt_pk_bf16_f32 on gfx950, else soft RNE.
__device__ __forceinline__ u32 pk_bf16(float a, float b) {
#if __has_builtin(__builtin_amdgcn_cvt_pk_bf16_f32)
    typedef __bf16 bf16x2_t __attribute__((ext_vector_type(2)));
    bf16x2_t t = __builtin_amdgcn_cvt_pk_bf16_f32(a, b);
    u32 r; __builtin_memcpy(&r, &t, 4); return r;
#else
    return (u32)f2bf(a) | ((u32)f2bf(b) << 16);
#endif
}
__device__ __forceinline__ u16 f2bf1(float f) { return (u16)(pk_bf16(f, f) & 0xffffu); }

// async global->LDS, 16B per lane; LDS dest = wave-uniform base + lane*16
__device__ __forceinline__ void gl2lds16(const void* g, void* l) {
    __builtin_amdgcn_global_load_lds(
        (const __attribute__((address_space(1))) u32*)(uintptr_t)g,
        (__attribute__((address_space(3))) u32*)(uintptr_t)l, 16, 0, 0);
}

// ---------------------------------------------------------------------------
// convert_in: fp32 -> bf16, flat copy of q,k,v (blockIdx.y selects tensor)
// ---------------------------------------------------------------------------
__global__ __launch_bounds__(256) void convert_in(
    const float* __restrict__ q, const float* __restrict__ k, const float* __restrict__ v,
    u16* __restrict__ dst)
{
    const float* src = (blockIdx.y == 0) ? q : (blockIdx.y == 1) ? k : v;
    u16* d = dst + (size_t)blockIdx.y * M * Dm;
    const size_t t = (size_t)blockIdx.x * 256 + threadIdx.x;
    const float4* s4 = reinterpret_cast<const float4*>(src) + t * 2;
    float4 f0 = s4[0], f1 = s4[1];
    u32 o[4] = { pk_bf16(f0.x, f0.y), pk_bf16(f0.z, f0.w),
                 pk_bf16(f1.x, f1.y), pk_bf16(f1.z, f1.w) };
    reinterpret_cast<uint4*>(d)[t] = *reinterpret_cast<uint4*>(o);
}

// ---------------------------------------------------------------------------
// convert_wt: fp32 W [K][N] -> bf16 W^T [N][K], 64x64 LDS tile. z selects W.
// ---------------------------------------------------------------------------
__global__ __launch_bounds__(256) void convert_wt(
    const float* __restrict__ Wq, const float* __restrict__ Wk,
    const float* __restrict__ Wv, const float* __restrict__ Wo,
    u16* __restrict__ dst)
{
    __shared__ u16 Ts[64][72];
    const int z = blockIdx.z;
    const float* W = (z == 0) ? Wq : (z == 1) ? Wk : (z == 2) ? Wv : Wo;
    u16* o = dst + (size_t)z * Dm * Dm;
    const int n0 = blockIdx.x * 64, k0 = blockIdx.y * 64;
    const int tid = threadIdx.x;

    {
        const int kr = tid >> 2, nc = (tid & 3) * 16;
        const float* s = W + (size_t)(k0 + kr) * Dm + n0 + nc;
        const float4* s4 = reinterpret_cast<const float4*>(s);
        float4 a = s4[0], b = s4[1], c = s4[2], d = s4[3];
        u32 t[8] = { pk_bf16(a.x, a.y), pk_bf16(a.z, a.w), pk_bf16(b.x, b.y), pk_bf16(b.z, b.w),
                     pk_bf16(c.x, c.y), pk_bf16(c.z, c.w), pk_bf16(d.x, d.y), pk_bf16(d.z, d.w) };
        *reinterpret_cast<uint4*>(&Ts[kr][nc])     = reinterpret_cast<uint4*>(t)[0];
        *reinterpret_cast<uint4*>(&Ts[kr][nc + 8]) = reinterpret_cast<uint4*>(t)[1];
    }
    __syncthreads();
    {
        const int nr = tid >> 2, kc = (tid & 3) * 16;
        u16 w[16];
        #pragma unroll
        for (int j = 0; j < 16; ++j) w[j] = Ts[kc + j][nr];
        u16* dptr = o + (size_t)(n0 + nr) * Dm + k0 + kc;
        *reinterpret_cast<uint4*>(dptr)     = reinterpret_cast<uint4*>(w)[0];
        *reinterpret_cast<uint4*>(dptr + 8) = reinterpret_cast<uint4*>(w)[1];
    }
}

// ---------------------------------------------------------------------------
// gemm_qkv: 128x128 tile m97 structure. z==2 writes V^T [B,H,DH,L] directly.
// ---------------------------------------------------------------------------
__global__ __launch_bounds__(256) void gemm_qkv(
    const u16* __restrict__ Abuf, const u16* __restrict__ Wtb,
    const float* __restrict__ bq, const float* __restrict__ bk, const float* __restrict__ bv,
    u16* __restrict__ Qh, u16* __restrict__ Kh, u16* __restrict__ Vth)
{
    __shared__ u16 As[128 * 32];
    __shared__ u16 Bs[128 * 32];
    const int tid = threadIdx.x;
    const int wave = tid >> 6, lane = tid & 63;
    const int quad = lane >> 4, l16 = lane & 15;
    const int wr = wave >> 1, wc = wave & 1;
    const int z = blockIdx.z;
    const u16* A  = Abuf + (size_t)z * M * Dm;
    const u16* Bt = Wtb  + (size_t)z * Dm * Dm;
    const float* bias = (z == 0) ? bq : (z == 1) ? bk : bv;
    u16* out = (z == 0) ? Qh : (z == 1) ? Kh : Vth;
    const int n0 = blockIdx.x * 128, m0 = blockIdx.y * 128;

    const int srow = lane >> 2;
    const int skc  = (lane & 3) * 8;

    f32x4 acc[4][4] = {};

    for (int k0 = 0; k0 < Dm; k0 += 32) {
        __syncthreads();
        #pragma unroll
        for (int i = 0; i < 2; ++i) {
            const int ra = i * 64 + wave * 16;
            gl2lds16(A  + (size_t)(m0 + ra + srow) * Dm + k0 + skc, &As[ra * 32]);
            gl2lds16(Bt + (size_t)(n0 + ra + srow) * Dm + k0 + skc, &Bs[ra * 32]);
        }
        __syncthreads();
        bf16x8 af[4], bf[4];
        #pragma unroll
        for (int t = 0; t < 4; ++t) {
            af[t] = *reinterpret_cast<const bf16x8*>(&As[(wr * 64 + t * 16 + l16) * 32 + quad * 8]);
            bf[t] = *reinterpret_cast<const bf16x8*>(&Bs[(wc * 64 + t * 16 + l16) * 32 + quad * 8]);
        }
        #pragma unroll
        for (int mt = 0; mt < 4; ++mt)
            #pragma unroll
            for (int nt = 0; nt < 4; ++nt)
                acc[mt][nt] = __builtin_amdgcn_mfma_f32_16x16x32_bf16(af[mt], bf[nt], acc[mt][nt], 0, 0, 0);
    }

    const float qscale = (z == 0) ? SC : 1.0f;
    #pragma unroll
    for (int nt = 0; nt < 4; ++nt) {
        const int n = n0 + wc * 64 + nt * 16 + l16;
        const float badd = bias[n];
        const int h = n >> 6, d = n & 63;
        #pragma unroll
        for (int mt = 0; mt < 4; ++mt) {
            const int mb = m0 + wr * 64 + mt * 16 + quad * 4;
            const int bb = mb >> 11, ll = mb & 2047;   // 4 consecutive m stay in-batch (mb%4==0)
            if (z == 2) {
                // V^T: addr = ((bb*H+h)*DH + d)*L + ll, consecutive over r -> pack b32
                u16* vp = out + (((size_t)(bb * H + h)) * DH + d) * L + ll;
                *reinterpret_cast<u32*>(vp)     = pk_bf16(acc[mt][nt][0] + badd, acc[mt][nt][1] + badd);
                *reinterpret_cast<u32*>(vp + 2) = pk_bf16(acc[mt][nt][2] + badd, acc[mt][nt][3] + badd);
            } else {
                #pragma unroll
                for (int r = 0; r < 4; ++r)
                    out[(((size_t)(bb * H + h)) * L + ll + r) * DH + d] =
                        f2bf1((acc[mt][nt][r] + badd) * qscale);
            }
        }
    }
}

// ---------------------------------------------------------------------------
// attn v4: 8 waves / 512 threads. Waves 0-3: even K-tiles, waves 4-7: odd
// K-tiles, same 128 q rows (wave w owns q-sub w&3). 2 tiles staged per round.
// End: partial-O merge via LDS (overlays dead KV buffers). S^T/O^T math and
// in-register P^T construction (permlane32_swap) as R3.
// ---------------------------------------------------------------------------
__global__ __launch_bounds__(512) void attn(
    const u16* __restrict__ Qh, const u16* __restrict__ Kh,
    const u16* __restrict__ Vth, u16* __restrict__ ctx)
{
    // smem map: [0,32768) KV staging (buf0: K@0 V@8192; buf1: K@16384 V@24576)
    //           merge overlay [0,34816): 4 qsubs x 64 lanes x 34 f32 (stride 136B)
    //           [34816,35840) rsum partials; [35840,45056) Os epilogue tile
    __shared__ __align__(16) char smem[45056];
    u16* Os = (u16*)(smem + 35840);
    float* rsums = (float*)(smem + 34816);

    const int tid  = threadIdx.x;
    const int w    = tid >> 6, lane = tid & 63;
    const int l31  = lane & 31, hh = lane >> 5;
    const int qt = blockIdx.x, h = blockIdx.y, b = blockIdx.z;
    const size_t hb = ((size_t)(b * H + h)) * L * DH;

    const int qsub  = w & 3;
    const int mybuf = w >> 2;
    const int q0 = qt * 128 + qsub * 32;

    // Q fragments (B operand), in regs
    bf16x8 qf[4];
    {
        const u16* qp = Qh + hb + (size_t)(q0 + l31) * DH + hh * 8;
        #pragma unroll
        for (int c = 0; c < 4; ++c)
            qf[c] = *reinterpret_cast<const bf16x8*>(qp + c * 16);
    }

    // staging: this wave fills one 8KB half-region, 4 insts x 1KB
    char* stbase = smem + (w >> 2) * 16384 + ((w >> 1) & 1) * 8192;
    const bool st_isK = ((w >> 1) & 1) == 0;
    const int row_half = (w & 1) * 32;
    const int rlane = lane >> 3;                 // row within 8-row group
    const int s_sw  = (lane & 7) ^ rlane;        // swizzled 16B slot -> source chunk

    // fragment-read bases (within own buffer)
    const char* ldsb = smem + mybuf * 16384;
    int vbK[2], vbV[2];
    #pragma unroll
    for (int t = 0; t < 2; ++t) {
        const int rr = t * 32 + l31;
        vbK[t] = rr * 128 + ((rr & 7) << 4);
        vbV[t] = 8192 + rr * 128 + ((rr & 7) << 4);
    }

    float rsum = 0.f;
    f32x16 oacc[2] = {};

    for (int r = 0; r < L / 128; ++r) {
        const int tile = 2 * r + mybuf;
        const int stile = 2 * r + (w >> 2);
        __syncthreads();
        #pragma unroll
        for (int i = 0; i < 4; ++i) {
            const int rloc = row_half + i * 8 + rlane;
            const void* src = st_isK
                ? (const void*)(Kh  + hb + (size_t)(stile * 64 + rloc) * DH + s_sw * 8)
                : (const void*)(Vth + hb + (size_t)rloc * L + stile * 64 + s_sw * 8);
            gl2lds16(src, stbase + (row_half + i * 8) * 128);
        }
        __syncthreads();

        // S^T = K @ Q^T
        f32x16 st[2] = {};
        #pragma unroll
        for (int t = 0; t < 2; ++t) {
            #pragma unroll
            for (int c = 0; c < 4; ++c) {
                bf16x8 kf = *reinterpret_cast<const bf16x8*>(ldsb + (vbK[t] ^ (((c << 1) | hh) << 4)));
                st[t] = __builtin_amdgcn_mfma_f32_32x32x16_bf16(kf, qf[c], st[t], 0, 0, 0);
            }
        }

        // P = exp2(S^T); P^T B-frags in-register via permlane32_swap + packed cvt
        bf16x8 pfrag[4];
        #pragma unroll
        for (int t = 0; t < 2; ++t) {
            float p[16];
            #pragma unroll
            for (int rr = 0; rr < 16; ++rr) {
                p[rr] = __builtin_amdgcn_exp2f(st[t][rr]);
                rsum += p[rr];
            }
            #pragma unroll
            for (int g = 0; g < 2; ++g) {
                float* pg = p + g * 8;
                #pragma unroll
                for (int j = 0; j < 4; ++j)
                    asm volatile("v_permlane32_swap_b32 %0, %1" : "+v"(pg[j]), "+v"(pg[j + 4]));
                u32 pkv[4];
                #pragma unroll
                for (int j = 0; j < 4; ++j) pkv[j] = pk_bf16(pg[2 * j], pg[2 * j + 1]);
                pfrag[t * 2 + g] = *reinterpret_cast<bf16x8*>(pkv);
            }
        }

        // O^T += V^T @ P^T
        #pragma unroll
        for (int t = 0; t < 2; ++t) {
            #pragma unroll
            for (int c = 0; c < 4; ++c) {
                bf16x8 vf = *reinterpret_cast<const bf16x8*>(ldsb + (vbV[t] ^ (((c << 1) | hh) << 4)));
                oacc[t] = __builtin_amdgcn_mfma_f32_32x32x16_bf16(vf, pfrag[c], oacc[t], 0, 0, 0);
            }
        }
    }

    // ---- merge partner halves (waves w and w+4 share q-sub, disjoint keys) ----
    __syncthreads();   // protect last round's KV reads before overlay write
    float* mb = (float*)smem + (size_t)qsub * 2176 + lane * 34;
    if (w >= 4) {
        #pragma unroll
        for (int t = 0; t < 2; ++t)
            #pragma unroll
            for (int rr = 0; rr < 16; ++rr) mb[t * 16 + rr] = oacc[t][rr];
        rsums[qsub * 64 + lane] = rsum;
    }
    __syncthreads();
    float inv = 0.f;
    if (w < 4) {
        #pragma unroll
        for (int t = 0; t < 2; ++t)
            #pragma unroll
            for (int rr = 0; rr < 16; ++rr) oacc[t][rr] += mb[t * 16 + rr];
        rsum += rsums[qsub * 64 + lane];
        rsum += __shfl_xor(rsum, 32);
        inv = 1.0f / rsum;
    }

    // ---- epilogue: O^T -> LDS transpose -> coalesced ctx store ----
    #pragma unroll
    for (int pass = 0; pass < 2; ++pass) {
        __syncthreads();
        if ((w >> 1) == pass) {          // waves {0,1} then {2,3}
            const int qloc = (w & 1) * 32 + l31;
            #pragma unroll
            for (int t = 0; t < 2; ++t) {
                #pragma unroll
                for (int rq = 0; rq < 4; ++rq) {
                    const int d0 = t * 32 + rq * 8 + hh * 4;
                    *reinterpret_cast<u32*>(&Os[qloc * 72 + d0]) =
                        pk_bf16(oacc[t][rq * 4 + 0] * inv, oacc[t][rq * 4 + 1] * inv);
                    *reinterpret_cast<u32*>(&Os[qloc * 72 + d0 + 2]) =
                        pk_bf16(oacc[t][rq * 4 + 2] * inv, oacc[t][rq * 4 + 3] * inv);
                }
            }
        }
        __syncthreads();
        {   // 512 threads store 64 rows x 128B
            const int row = tid >> 3, cc = (tid & 7) * 8;
            u16* dst = ctx + ((size_t)(b * L + qt * 128 + pass * 64 + row)) * Dm + h * 64 + cc;
            *reinterpret_cast<uint4*>(dst) = *reinterpret_cast<const uint4*>(&Os[row * 72 + cc]);
        }
    }
}

// ---------------------------------------------------------------------------
// gemm_out: out = ctx(bf16 [M][K]) @ Wot^T + bo -> fp32.  128x64 tiles.
// ---------------------------------------------------------------------------
__global__ __launch_bounds__(256) void gemm_out(
    const u16* __restrict__ A, const u16* __restrict__ Bt,
    const float* __restrict__ bias, float* __restrict__ out)
{
    __shared__ u16 As[128 * 32];
    __shared__ u16 Bs[64 * 32];
    const int tid = threadIdx.x;
    const int wave = tid >> 6, lane = tid & 63;
    const int quad = lane >> 4, l16 = lane & 15;
    const int n0 = blockIdx.x * 64, m0 = blockIdx.y * 128;

    const int srow = lane >> 2;
    const int skc  = (lane & 3) * 8;

    f32x4 acc[2][4] = {};

    for (int k0 = 0; k0 < Dm; k0 += 32) {
        __syncthreads();
        #pragma unroll
        for (int i = 0; i < 2; ++i) {
            const int ra = i * 64 + wave * 16;
            gl2lds16(A + (size_t)(m0 + ra + srow) * Dm + k0 + skc, &As[ra * 32]);
        }
        gl2lds16(Bt + (size_t)(n0 + wave * 16 + srow) * Dm + k0 + skc, &Bs[wave * 16 * 32]);
        __syncthreads();
        bf16x8 af[2], bf[4];
        #pragma unroll
        for (int t = 0; t < 2; ++t)
            af[t] = *reinterpret_cast<const bf16x8*>(&As[(wave * 32 + t * 16 + l16) * 32 + quad * 8]);
        #pragma unroll
        for (int t = 0; t < 4; ++t)
            bf[t] = *reinterpret_cast<const bf16x8*>(&Bs[(t * 16 + l16) * 32 + quad * 8]);
        #pragma unroll
        for (int mt = 0; mt < 2; ++mt)
            #pragma unroll
            for (int nt = 0; nt < 4; ++nt)
                acc[mt][nt] = __builtin_amdgcn_mfma_f32_16x16x32_bf16(af[mt], bf[nt], acc[mt][nt], 0, 0, 0);
    }

    #pragma unroll
    for (int nt = 0; nt < 4; ++nt) {
        const int n = n0 + nt * 16 + l16;
        const float badd = bias[n];
        #pragma unroll
        for (int mt = 0; mt < 2; ++mt) {
            #pragma unroll
            for (int r = 0; r < 4; ++r) {
                const int m = m0 + wave * 32 + mt * 16 + quad * 4 + r;
                out[(size_t)m * Dm + n] = acc[mt][nt][r] + badd;
            }
        }
    }
}

// ---------------------------------------------------------------------------
extern "C" void kernel_launch(void* const* d_in, const int* in_sizes, int n_in,
                              void* d_out, int out_size, void* d_ws, size_t ws_size,
                              hipStream_t stream) {
    const float* q  = (const float*)d_in[0];
    const float* k  = (const float*)d_in[1];
    const float* v  = (const float*)d_in[2];
    const float* Wq = (const float*)d_in[3];
    const float* bq = (const float*)d_in[4];
    const float* Wk = (const float*)d_in[5];
    const float* bk = (const float*)d_in[6];
    const float* Wv = (const float*)d_in[7];
    const float* bv = (const float*)d_in[8];
    const float* Wo = (const float*)d_in[9];
    const float* bo = (const float*)d_in[10];
    float* out = (float*)d_out;

    const size_t per = (size_t)Bn * H * L * DH;   // 4M elems
    u16* Abuf = (u16*)d_ws;
    u16* Wt   = Abuf + 3 * (size_t)M * Dm;
    u16* Qh   = Wt + 4 * (size_t)Dm * Dm;
    u16* Kh   = Qh + per;
    u16* Vth  = Kh + per;
    u16* ctx  = Abuf;   // overlay (Abuf dead after gemm_qkv)

    convert_in <<<dim3((M * Dm) / 8 / 256, 3), 256, 0, stream>>>(q, k, v, Abuf);
    convert_wt <<<dim3(Dm / 64, Dm / 64, 4), 256, 0, stream>>>(Wq, Wk, Wv, Wo, Wt);
    gemm_qkv   <<<dim3(Dm / 128, M / 128, 3), 256, 0, stream>>>(Abuf, Wt, bq, bk, bv, Qh, Kh, Vth);
    attn       <<<dim3(L / 128, H, Bn), 512, 0, stream>>>(Qh, Kh, Vth, ctx);
    gemm_out   <<<dim3(Dm / 64, M / 128), 256, 0, stream>>>(ctx, Wt + 3 * (size_t)Dm * Dm, bo, out);
}

// Round 5
// 237.847 us; speedup vs baseline: 1.1099x; 1.1099x over previous
//
#include <hip/hip_runtime.h>
#include <cstdint>
#include <cstddef>

typedef __bf16 bf16x8 __attribute__((ext_vector_type(8)));
typedef float f32x4 __attribute__((ext_vector_type(4)));
typedef float f32x16 __attribute__((ext_vector_type(16)));
typedef unsigned short u16;
typedef unsigned int u32;

static constexpr int Bn = 2;       // batch
static constexpr int L  = 2048;    // sequence
static constexpr int Dm = 1024;    // model dim
static constexpr int H  = 16;      // heads
static constexpr int DH = 64;      // head dim
static constexpr int M  = Bn * L;  // 4096 rows

#define SC 0.18033688f   /* 0.125 * log2(e): folded into Q so QK^T is in exp2 domain */

__device__ __forceinline__ u16 f2bf(float f) {
    union { float f; u32 u; } v; v.f = f;
    u32 u = v.u + 0x7FFFu + ((v.u >> 16) & 1u);   // RNE
    return (u16)(u >> 16);
}

// packed f32x2 -> bf16x2 (low = a). HW v_cvt_pk_bf16_f32 on gfx950.
__device__ __forceinline__ u32 pk_bf16(float a, float b) {
#if __has_builtin(__builtin_amdgcn_cvt_pk_bf16_f32)
    typedef __bf16 bf16x2_t __attribute__((ext_vector_type(2)));
    bf16x2_t t = __builtin_amdgcn_cvt_pk_bf16_f32(a, b);
    u32 r; __builtin_memcpy(&r, &t, 4); return r;
#else
    return (u32)f2bf(a) | ((u32)f2bf(b) << 16);
#endif
}
__device__ __forceinline__ u16 f2bf1(float f) { return (u16)(pk_bf16(f, f) & 0xffffu); }

// async global->LDS, 16B per lane; LDS dest = wave-uniform base + lane*16
__device__ __forceinline__ void gl2lds16(const void* g, void* l) {
    __builtin_amdgcn_global_load_lds(
        (const __attribute__((address_space(1))) u32*)(uintptr_t)g,
        (__attribute__((address_space(3))) u32*)(uintptr_t)l, 16, 0, 0);
}

// ---------------------------------------------------------------------------
// convert_in: fp32 -> bf16, flat copy of q,k,v (blockIdx.y selects tensor)
// ---------------------------------------------------------------------------
__global__ __launch_bounds__(256) void convert_in(
    const float* __restrict__ q, const float* __restrict__ k, const float* __restrict__ v,
    u16* __restrict__ dst)
{
    const float* src = (blockIdx.y == 0) ? q : (blockIdx.y == 1) ? k : v;
    u16* d = dst + (size_t)blockIdx.y * M * Dm;
    const size_t t = (size_t)blockIdx.x * 256 + threadIdx.x;
    const float4* s4 = reinterpret_cast<const float4*>(src) + t * 2;
    float4 f0 = s4[0], f1 = s4[1];
    u32 o[4] = { pk_bf16(f0.x, f0.y), pk_bf16(f0.z, f0.w),
                 pk_bf16(f1.x, f1.y), pk_bf16(f1.z, f1.w) };
    reinterpret_cast<uint4*>(d)[t] = *reinterpret_cast<uint4*>(o);
}

// ---------------------------------------------------------------------------
// convert_wt: fp32 W [K][N] -> bf16 W^T [N][K], 64x64 LDS tile. z selects W.
// ---------------------------------------------------------------------------
__global__ __launch_bounds__(256) void convert_wt(
    const float* __restrict__ Wq, const float* __restrict__ Wk,
    const float* __restrict__ Wv, const float* __restrict__ Wo,
    u16* __restrict__ dst)
{
    __shared__ u16 Ts[64][72];
    const int z = blockIdx.z;
    const float* W = (z == 0) ? Wq : (z == 1) ? Wk : (z == 2) ? Wv : Wo;
    u16* o = dst + (size_t)z * Dm * Dm;
    const int n0 = blockIdx.x * 64, k0 = blockIdx.y * 64;
    const int tid = threadIdx.x;

    {
        const int kr = tid >> 2, nc = (tid & 3) * 16;
        const float* s = W + (size_t)(k0 + kr) * Dm + n0 + nc;
        const float4* s4 = reinterpret_cast<const float4*>(s);
        float4 a = s4[0], b = s4[1], c = s4[2], d = s4[3];
        u32 t[8] = { pk_bf16(a.x, a.y), pk_bf16(a.z, a.w), pk_bf16(b.x, b.y), pk_bf16(b.z, b.w),
                     pk_bf16(c.x, c.y), pk_bf16(c.z, c.w), pk_bf16(d.x, d.y), pk_bf16(d.z, d.w) };
        *reinterpret_cast<uint4*>(&Ts[kr][nc])     = reinterpret_cast<uint4*>(t)[0];
        *reinterpret_cast<uint4*>(&Ts[kr][nc + 8]) = reinterpret_cast<uint4*>(t)[1];
    }
    __syncthreads();
    {
        const int nr = tid >> 2, kc = (tid & 3) * 16;
        u16 w[16];
        #pragma unroll
        for (int j = 0; j < 16; ++j) w[j] = Ts[kc + j][nr];
        u16* dptr = o + (size_t)(n0 + nr) * Dm + k0 + kc;
        *reinterpret_cast<uint4*>(dptr)     = reinterpret_cast<uint4*>(w)[0];
        *reinterpret_cast<uint4*>(dptr + 8) = reinterpret_cast<uint4*>(w)[1];
    }
}

// ---------------------------------------------------------------------------
// gemm_qkv: 128x128 tile, BK=32, double-buffered single-barrier K-loop.
// Outputs bf16 head-split [B,H,L,DH]; Q scaled by SC.
// ---------------------------------------------------------------------------
__global__ __launch_bounds__(256) void gemm_qkv(
    const u16* __restrict__ Abuf, const u16* __restrict__ Wtb,
    const float* __restrict__ bq, const float* __restrict__ bk, const float* __restrict__ bv,
    u16* __restrict__ Qh, u16* __restrict__ Kh, u16* __restrict__ Vh)
{
    __shared__ u16 As[2][128 * 32];
    __shared__ u16 Bs[2][128 * 32];
    const int tid = threadIdx.x;
    const int wave = tid >> 6, lane = tid & 63;
    const int quad = lane >> 4, l16 = lane & 15;
    const int wr = wave >> 1, wc = wave & 1;
    const int z = blockIdx.z;
    const u16* A  = Abuf + (size_t)z * M * Dm;
    const u16* Bt = Wtb  + (size_t)z * Dm * Dm;
    const float* bias = (z == 0) ? bq : (z == 1) ? bk : bv;
    u16* out = (z == 0) ? Qh : (z == 1) ? Kh : Vh;
    const int n0 = blockIdx.x * 128, m0 = blockIdx.y * 128;

    const int srow = lane >> 2;
    const int skc  = (lane & 3) * 8;

    f32x4 acc[4][4] = {};

    auto stage = [&](int k0, int bi) {
        #pragma unroll
        for (int i = 0; i < 2; ++i) {
            const int ra = i * 64 + wave * 16;
            gl2lds16(A  + (size_t)(m0 + ra + srow) * Dm + k0 + skc, &As[bi][ra * 32]);
            gl2lds16(Bt + (size_t)(n0 + ra + srow) * Dm + k0 + skc, &Bs[bi][ra * 32]);
        }
    };

    stage(0, 0);
    for (int k0 = 0, it = 0; k0 < Dm; k0 += 32, ++it) {
        const int cb = it & 1;
        __syncthreads();                       // buf[cb] ready; prior reads of buf[cb^1] done
        if (k0 + 32 < Dm) stage(k0 + 32, cb ^ 1);
        bf16x8 af[4], bf[4];
        #pragma unroll
        for (int t = 0; t < 4; ++t) {
            af[t] = *reinterpret_cast<const bf16x8*>(&As[cb][(wr * 64 + t * 16 + l16) * 32 + quad * 8]);
            bf[t] = *reinterpret_cast<const bf16x8*>(&Bs[cb][(wc * 64 + t * 16 + l16) * 32 + quad * 8]);
        }
        #pragma unroll
        for (int mt = 0; mt < 4; ++mt)
            #pragma unroll
            for (int nt = 0; nt < 4; ++nt)
                acc[mt][nt] = __builtin_amdgcn_mfma_f32_16x16x32_bf16(af[mt], bf[nt], acc[mt][nt], 0, 0, 0);
    }

    const float qscale = (z == 0) ? SC : 1.0f;
    #pragma unroll
    for (int nt = 0; nt < 4; ++nt) {
        const int n = n0 + wc * 64 + nt * 16 + l16;
        const float badd = bias[n];
        const int h = n >> 6, d = n & 63;
        #pragma unroll
        for (int mt = 0; mt < 4; ++mt) {
            #pragma unroll
            for (int r = 0; r < 4; ++r) {
                const int m = m0 + wr * 64 + mt * 16 + quad * 4 + r;
                const int bb = m >> 11, ll = m & 2047;
                out[(((size_t)(bb * H + h)) * L + ll) * DH + d] = f2bf1((acc[mt][nt][r] + badd) * qscale);
            }
        }
    }
}

// ---------------------------------------------------------------------------
// transpose_v: Vh [B,H,L,DH] -> Vth [B,H,DH,L]  (coalesced both sides)
// ---------------------------------------------------------------------------
__global__ __launch_bounds__(256) void transpose_v(
    const u16* __restrict__ Vh, u16* __restrict__ Vth)
{
    __shared__ u16 Ts[64][72];
    const int kt = blockIdx.x, h = blockIdx.y, b = blockIdx.z;
    const int tid = threadIdx.x;
    const size_t hb = ((size_t)(b * H + h)) * L * DH;

    {
        const int kr = tid >> 2, dc = (tid & 3) * 16;
        const u16* s = Vh + hb + (size_t)(kt * 64 + kr) * DH + dc;
        *reinterpret_cast<uint4*>(&Ts[kr][dc])     = *reinterpret_cast<const uint4*>(s);
        *reinterpret_cast<uint4*>(&Ts[kr][dc + 8]) = *reinterpret_cast<const uint4*>(s + 8);
    }
    __syncthreads();
    {
        const int dr = tid >> 2, kc = (tid & 3) * 16;
        u16 w[16];
        #pragma unroll
        for (int j = 0; j < 16; ++j) w[j] = Ts[kc + j][dr];
        u16* dptr = Vth + hb + (size_t)dr * L + kt * 64 + kc;
        *reinterpret_cast<uint4*>(dptr)     = reinterpret_cast<uint4*>(w)[0];
        *reinterpret_cast<uint4*>(dptr + 8) = reinterpret_cast<uint4*>(w)[1];
    }
}

// ---------------------------------------------------------------------------
// attn v5: R3 structure (4 waves, wave owns 32 q x all keys) + double-buffered
// single-barrier K-loop + HW bf16 packing. S^T = K@Q^T, O^T = V^T@P^T
// (32x32x16 MFMA); P^T built in-register via v_permlane32_swap_b32.
// ---------------------------------------------------------------------------
__global__ __launch_bounds__(256) void attn(
    const u16* __restrict__ Qh, const u16* __restrict__ Kh,
    const u16* __restrict__ Vth, u16* __restrict__ ctx)
{
    // two 16KB KV buffers: buf i at smem+i*16384, K@+0, V@+8192 (swizzled 128B rows)
    // epilogue Os (64x72 u16 = 9216B) overlays buf0 (dead: last tile is odd).
    __shared__ __align__(16) char smem[32768];
    u16* Os = (u16*)smem;

    const int tid  = threadIdx.x;
    const int wave = tid >> 6, lane = tid & 63;
    const int l31  = lane & 31, hh = lane >> 5;
    const int qt = blockIdx.x, h = blockIdx.y, b = blockIdx.z;
    const size_t hb = ((size_t)(b * H + h)) * L * DH;
    const int q0 = qt * 128 + wave * 32;

    // Q fragments (B operand: n=q=lane&31, k=8*hh+j within 16-chunk), in regs
    bf16x8 qf[4];
    {
        const u16* qp = Qh + hb + (size_t)(q0 + l31) * DH + hh * 8;
        #pragma unroll
        for (int c = 0; c < 4; ++c)
            qf[c] = *reinterpret_cast<const bf16x8*>(qp + c * 16);
    }

    const int r_off = lane >> 3;      // row within 8-row group
    const int s_sl  = lane & 7;       // 16B slot

    auto stage = [&](int kt, int bi) {
        char* base = smem + bi * 16384;
        #pragma unroll
        for (int i = 0; i < 2; ++i) {
            const int rr = wave * 16 + i * 8 + r_off;
            gl2lds16(Kh  + hb + (size_t)(kt * 64 + rr) * DH + ((s_sl ^ (rr & 7)) << 3),
                     base + (wave * 16 + i * 8) * 128);
            gl2lds16(Vth + hb + (size_t)rr * L + kt * 64 + ((s_sl ^ (rr & 7)) << 3),
                     base + 8192 + (wave * 16 + i * 8) * 128);
        }
    };

    // fragment-read byte bases (swizzled): addr = base ^ ((2c+hh)<<4)
    int vbK[2], vbV[2];
    #pragma unroll
    for (int t = 0; t < 2; ++t) {
        const int rr = t * 32 + l31;
        vbK[t] = rr * 128 + ((rr & 7) << 4);
        vbV[t] = 8192 + rr * 128 + ((rr & 7) << 4);
    }

    float rsum = 0.f;
    f32x16 oacc[2] = {};

    stage(0, 0);
    for (int kt = 0; kt < L / 64; ++kt) {
        const int cb = kt & 1;
        __syncthreads();                       // buf[cb] staged; prior reads of buf[cb^1] done
        if (kt + 1 < L / 64) stage(kt + 1, cb ^ 1);
        const char* ldsb = smem + cb * 16384;

        // S^T = K @ Q^T
        f32x16 st[2] = {};
        #pragma unroll
        for (int t = 0; t < 2; ++t) {
            #pragma unroll
            for (int c = 0; c < 4; ++c) {
                bf16x8 kf = *reinterpret_cast<const bf16x8*>(ldsb + (vbK[t] ^ (((c << 1) | hh) << 4)));
                st[t] = __builtin_amdgcn_mfma_f32_32x32x16_bf16(kf, qf[c], st[t], 0, 0, 0);
            }
        }

        // P = exp2(S^T); P^T B-frags in-register via permlane32_swap + packed cvt
        bf16x8 pfrag[4];
        #pragma unroll
        for (int t = 0; t < 2; ++t) {
            float p[16];
            #pragma unroll
            for (int rr = 0; rr < 16; ++rr) {
                p[rr] = __builtin_amdgcn_exp2f(st[t][rr]);
                rsum += p[rr];
            }
            #pragma unroll
            for (int g = 0; g < 2; ++g) {
                float* pg = p + g * 8;
                #pragma unroll
                for (int j = 0; j < 4; ++j)
                    asm volatile("v_permlane32_swap_b32 %0, %1" : "+v"(pg[j]), "+v"(pg[j + 4]));
                u32 pkv[4];
                #pragma unroll
                for (int j = 0; j < 4; ++j) pkv[j] = pk_bf16(pg[2 * j], pg[2 * j + 1]);
                pfrag[t * 2 + g] = *reinterpret_cast<bf16x8*>(pkv);
            }
        }

        // O^T += V^T @ P^T
        #pragma unroll
        for (int t = 0; t < 2; ++t) {
            #pragma unroll
            for (int c = 0; c < 4; ++c) {
                bf16x8 vf = *reinterpret_cast<const bf16x8*>(ldsb + (vbV[t] ^ (((c << 1) | hh) << 4)));
                oacc[t] = __builtin_amdgcn_mfma_f32_32x32x16_bf16(vf, pfrag[c], oacc[t], 0, 0, 0);
            }
        }
    }

    rsum += __shfl_xor(rsum, 32);
    const float inv = 1.0f / rsum;

    // epilogue: O^T -> LDS transpose (Os overlays buf0) -> coalesced ctx store
    #pragma unroll
    for (int pass = 0; pass < 2; ++pass) {
        __syncthreads();
        if ((wave >> 1) == pass) {          // waves {0,1} then {2,3}
            const int qloc = (wave & 1) * 32 + l31;
            #pragma unroll
            for (int t = 0; t < 2; ++t) {
                #pragma unroll
                for (int rq = 0; rq < 4; ++rq) {
                    const int d0 = t * 32 + rq * 8 + hh * 4;
                    *reinterpret_cast<u32*>(&Os[qloc * 72 + d0]) =
                        pk_bf16(oacc[t][rq * 4 + 0] * inv, oacc[t][rq * 4 + 1] * inv);
                    *reinterpret_cast<u32*>(&Os[qloc * 72 + d0 + 2]) =
                        pk_bf16(oacc[t][rq * 4 + 2] * inv, oacc[t][rq * 4 + 3] * inv);
                }
            }
        }
        __syncthreads();
        {
            const int row = tid >> 2, cc = (tid & 3) * 16;
            u16* dst = ctx + ((size_t)(b * L + qt * 128 + pass * 64 + row)) * Dm + h * 64 + cc;
            *reinterpret_cast<uint4*>(dst)     = *reinterpret_cast<const uint4*>(&Os[row * 72 + cc]);
            *reinterpret_cast<uint4*>(dst + 8) = *reinterpret_cast<const uint4*>(&Os[row * 72 + cc + 8]);
        }
    }
}

// ---------------------------------------------------------------------------
// gemm_out: out = ctx(bf16 [M][K]) @ Wot^T + bo -> fp32.  128x64 tiles,
// double-buffered single-barrier K-loop.
// ---------------------------------------------------------------------------
__global__ __launch_bounds__(256) void gemm_out(
    const u16* __restrict__ A, const u16* __restrict__ Bt,
    const float* __restrict__ bias, float* __restrict__ out)
{
    __shared__ u16 As[2][128 * 32];
    __shared__ u16 Bs[2][64 * 32];
    const int tid = threadIdx.x;
    const int wave = tid >> 6, lane = tid & 63;
    const int quad = lane >> 4, l16 = lane & 15;
    const int n0 = blockIdx.x * 64, m0 = blockIdx.y * 128;

    const int srow = lane >> 2;
    const int skc  = (lane & 3) * 8;

    f32x4 acc[2][4] = {};

    auto stage = [&](int k0, int bi) {
        #pragma unroll
        for (int i = 0; i < 2; ++i) {
            const int ra = i * 64 + wave * 16;
            gl2lds16(A + (size_t)(m0 + ra + srow) * Dm + k0 + skc, &As[bi][ra * 32]);
        }
        gl2lds16(Bt + (size_t)(n0 + wave * 16 + srow) * Dm + k0 + skc, &Bs[bi][wave * 16 * 32]);
    };

    stage(0, 0);
    for (int k0 = 0, it = 0; k0 < Dm; k0 += 32, ++it) {
        const int cb = it & 1;
        __syncthreads();
        if (k0 + 32 < Dm) stage(k0 + 32, cb ^ 1);
        bf16x8 af[2], bf[4];
        #pragma unroll
        for (int t = 0; t < 2; ++t)
            af[t] = *reinterpret_cast<const bf16x8*>(&As[cb][(wave * 32 + t * 16 + l16) * 32 + quad * 8]);
        #pragma unroll
        for (int t = 0; t < 4; ++t)
            bf[t] = *reinterpret_cast<const bf16x8*>(&Bs[cb][(t * 16 + l16) * 32 + quad * 8]);
        #pragma unroll
        for (int mt = 0; mt < 2; ++mt)
            #pragma unroll
            for (int nt = 0; nt < 4; ++nt)
                acc[mt][nt] = __builtin_amdgcn_mfma_f32_16x16x32_bf16(af[mt], bf[nt], acc[mt][nt], 0, 0, 0);
    }

    #pragma unroll
    for (int nt = 0; nt < 4; ++nt) {
        const int n = n0 + nt * 16 + l16;
        const float badd = bias[n];
        #pragma unroll
        for (int mt = 0; mt < 2; ++mt) {
            #pragma unroll
            for (int r = 0; r < 4; ++r) {
                const int m = m0 + wave * 32 + mt * 16 + quad * 4 + r;
                out[(size_t)m * Dm + n] = acc[mt][nt][r] + badd;
            }
        }
    }
}

// ---------------------------------------------------------------------------
extern "C" void kernel_launch(void* const* d_in, const int* in_sizes, int n_in,
                              void* d_out, int out_size, void* d_ws, size_t ws_size,
                              hipStream_t stream) {
    const float* q  = (const float*)d_in[0];
    const float* k  = (const float*)d_in[1];
    const float* v  = (const float*)d_in[2];
    const float* Wq = (const float*)d_in[3];
    const float* bq = (const float*)d_in[4];
    const float* Wk = (const float*)d_in[5];
    const float* bk = (const float*)d_in[6];
    const float* Wv = (const float*)d_in[7];
    const float* bv = (const float*)d_in[8];
    const float* Wo = (const float*)d_in[9];
    const float* bo = (const float*)d_in[10];
    float* out = (float*)d_out;

    const size_t per = (size_t)Bn * H * L * DH;   // 4M elems
    u16* Abuf = (u16*)d_ws;
    u16* Wt   = Abuf + 3 * (size_t)M * Dm;
    u16* Qh   = Wt + 4 * (size_t)Dm * Dm;
    u16* Kh   = Qh + per;
    u16* Vh   = Kh + per;
    u16* Vth  = Vh + per;
    u16* ctx  = Abuf;   // overlay (Abuf dead after gemm_qkv)

    convert_in <<<dim3((M * Dm) / 8 / 256, 3), 256, 0, stream>>>(q, k, v, Abuf);
    convert_wt <<<dim3(Dm / 64, Dm / 64, 4), 256, 0, stream>>>(Wq, Wk, Wv, Wo, Wt);
    gemm_qkv   <<<dim3(Dm / 128, M / 128, 3), 256, 0, stream>>>(Abuf, Wt, bq, bk, bv, Qh, Kh, Vh);
    transpose_v<<<dim3(L / 64, H, Bn), 256, 0, stream>>>(Vh, Vth);
    attn       <<<dim3(L / 128, H, Bn), 256, 0, stream>>>(Qh, Kh, Vth, ctx);
    gemm_out   <<<dim3(Dm / 64, M / 128), 256, 0, stream>>>(ctx, Wt + 3 * (size_t)Dm * Dm, bo, out);
}